// Round 2
// baseline (2622.633 us; speedup 1.0000x reference)
//
#include <hip/hip_runtime.h>
#include <math.h>

#define N_NODES 100000
#define N_EDGES 1600000
#define EP (N_EDGES + N_NODES)   // edges + self-loops = 1,700,000
#define NH 8
#define NC 64
#define NG 64
#define HC 512
#define SCAN_BLOCKS ((N_NODES + 255) / 256)   // 391
#define NSLICE 16
#define SLICE_ROWS (N_NODES / NSLICE)         // 6250
#define NPART 32                              // pooling atomic partitions

typedef unsigned short bf16_t;

__device__ inline float bf2f(bf16_t u) {
    union { unsigned int i; float f; } x;
    x.i = (unsigned int)u << 16;
    return x.f;
}
__device__ inline bf16_t f2bf(float f) {
    union { float f; unsigned int i; } x;
    x.f = f;
    unsigned int b = x.i;
    return (bf16_t)((b + 0x7fffu + ((b >> 16) & 1u)) >> 16);
}

// ---------------- prep: ws1[h][k] = sum_c W1[k][h*64+c]*a1s[h][c]; wd1 likewise ----------------
__global__ void k_prep(const float* __restrict__ W1, const float* __restrict__ a1s,
                       const float* __restrict__ a1d, float* __restrict__ wprep) {
    int t = threadIdx.x;  // need 48
    if (t < 48) {
        int isD = t >= 24;
        int tt = t % 24;
        int h = tt / 3, k = tt % 3;
        const float* a = isD ? a1d : a1s;
        float s = 0.f;
        for (int c = 0; c < 64; c++) s += W1[k * HC + h * 64 + c] * a[h * 64 + c];
        wprep[t] = s;  // [0..23]=ws1[h*3+k], [24..47]=wd1
    }
}

// ---------------- CSR build ----------------
__global__ void k_deg(const int* __restrict__ ei, int* __restrict__ deg) {
    int i = blockIdx.x * 256 + threadIdx.x;
    if (i >= EP) return;
    int d = (i < N_EDGES) ? ei[N_EDGES + i] : (i - N_EDGES);
    atomicAdd(&deg[d], 1);
}

__global__ void k_scan1(const int* __restrict__ deg, int* __restrict__ rowptr, int* __restrict__ part) {
    __shared__ int s[256];
    int t = threadIdx.x, i = blockIdx.x * 256 + t;
    int v = (i < N_NODES) ? deg[i] : 0;
    s[t] = v;
    __syncthreads();
    for (int off = 1; off < 256; off <<= 1) {
        int u = (t >= off) ? s[t - off] : 0;
        __syncthreads();
        s[t] += u;
        __syncthreads();
    }
    if (i < N_NODES) rowptr[i] = s[t] - v;  // exclusive
    if (t == 255) part[blockIdx.x] = s[t];
}

__global__ void k_scan2(int* __restrict__ part, int* __restrict__ rowptr) {
    __shared__ int s[512];
    int t = threadIdx.x;
    int v = (t < SCAN_BLOCKS) ? part[t] : 0;
    s[t] = v;
    __syncthreads();
    for (int off = 1; off < 512; off <<= 1) {
        int u = (t >= off) ? s[t - off] : 0;
        __syncthreads();
        s[t] += u;
        __syncthreads();
    }
    part[t] = s[t] - v;  // exclusive
    if (t == 0) rowptr[N_NODES] = EP;
}

__global__ void k_scan3(const int* __restrict__ part, int* __restrict__ rowptr) {
    int i = blockIdx.x * 256 + threadIdx.x;
    if (i < N_NODES) rowptr[i] += part[blockIdx.x];
}

__global__ void k_scatter(const int* __restrict__ ei, const int* __restrict__ rowptr,
                          int* __restrict__ cursor, int* __restrict__ csr) {
    int i = blockIdx.x * 256 + threadIdx.x;
    if (i >= EP) return;
    int s, d;
    if (i < N_EDGES) { s = ei[i]; d = ei[N_EDGES + i]; }
    else { s = i - N_EDGES; d = s; }
    int pos = rowptr[d] + atomicAdd(&cursor[d], 1);
    csr[pos] = s;
}

// ---------------- layer 1 (fused: rank-3 trick, no h1 materialization), bf16 output --------
__global__ __launch_bounds__(256) void k_layer1(
    const float* __restrict__ x, const int* __restrict__ rowptr, const int* __restrict__ csr,
    const float* __restrict__ W1, const float* __restrict__ wprep, const float* __restrict__ b1,
    bf16_t* __restrict__ x1) {
    __shared__ float w1s[1536];
    __shared__ float wp[48];
    int tid = threadIdx.x;
    for (int i = tid; i < 1536; i += 256) w1s[i] = W1[i];
    if (tid < 48) wp[tid] = wprep[tid];
    __syncthreads();
    int lane = tid & 63;
    int dst = (blockIdx.x * 256 + tid) >> 6;  // grid exactly covers N
    int rs = rowptr[dst], re = rowptr[dst + 1];
    float xd0 = x[dst * 3], xd1 = x[dst * 3 + 1], xd2 = x[dst * 3 + 2];
    float ald[NH];
#pragma unroll
    for (int h = 0; h < NH; h++)
        ald[h] = xd0 * wp[24 + h * 3] + xd1 * wp[24 + h * 3 + 1] + xd2 * wp[24 + h * 3 + 2];
    // pass 1: per-head max
    float m[NH];
#pragma unroll
    for (int h = 0; h < NH; h++) m[h] = -1e30f;
    for (int base = rs; base < re; base += 64) {
        int e = base + lane;
        if (e < re) {
            int s = csr[e];
            float s0 = x[s * 3], s1 = x[s * 3 + 1], s2 = x[s * 3 + 2];
#pragma unroll
            for (int h = 0; h < NH; h++) {
                float ev = s0 * wp[h * 3] + s1 * wp[h * 3 + 1] + s2 * wp[h * 3 + 2] + ald[h];
                ev = ev > 0.f ? ev : 0.2f * ev;
                m[h] = fmaxf(m[h], ev);
            }
        }
    }
#pragma unroll
    for (int h = 0; h < NH; h++)
#pragma unroll
        for (int off = 1; off < 64; off <<= 1) m[h] = fmaxf(m[h], __shfl_xor(m[h], off, 64));
    // pass 2: den + 3-vector accumulators
    float den[NH], c0[NH], c1[NH], c2[NH];
#pragma unroll
    for (int h = 0; h < NH; h++) { den[h] = 0.f; c0[h] = 0.f; c1[h] = 0.f; c2[h] = 0.f; }
    for (int base = rs; base < re; base += 64) {
        int e = base + lane;
        if (e < re) {
            int s = csr[e];
            float s0 = x[s * 3], s1 = x[s * 3 + 1], s2 = x[s * 3 + 2];
#pragma unroll
            for (int h = 0; h < NH; h++) {
                float ev = s0 * wp[h * 3] + s1 * wp[h * 3 + 1] + s2 * wp[h * 3 + 2] + ald[h];
                ev = ev > 0.f ? ev : 0.2f * ev;
                float w = expf(ev - m[h]);
                den[h] += w;
                c0[h] += w * s0;
                c1[h] += w * s1;
                c2[h] += w * s2;
            }
        }
    }
#pragma unroll
    for (int h = 0; h < NH; h++) {
#pragma unroll
        for (int off = 1; off < 64; off <<= 1) {
            den[h] += __shfl_xor(den[h], off, 64);
            c0[h] += __shfl_xor(c0[h], off, 64);
            c1[h] += __shfl_xor(c1[h], off, 64);
            c2[h] += __shfl_xor(c2[h], off, 64);
        }
    }
    // epilogue: project 3-vec through W1 head-slice, bias, ELU, store bf16
#pragma unroll
    for (int h = 0; h < NH; h++) {
        int col = h * 64 + lane;
        float v = c0[h] * w1s[col] + c1[h] * w1s[512 + col] + c2[h] * w1s[1024 + col];
        v = v / den[h] + b1[col];
        v = v > 0.f ? v : expm1f(v);
        x1[(size_t)dst * HC + col] = f2bf(v);
    }
}

// ---------------- GEMM2 slice: T = x1[row_base:+SLICE_ROWS] @ W2 (bf16 A, fp32 math) -------
__global__ __launch_bounds__(256) void k_gemm2(const bf16_t* __restrict__ A, const float* __restrict__ B,
                                               bf16_t* __restrict__ T, int row_base) {
    __shared__ float As[16 * 132];
    __shared__ float Bs[16 * 132];
    int tid = threadIdx.x;
    int gx = blockIdx.x;  // 0..3 col block
    int gy = blockIdx.y;  // row block within slice
    int tx = tid & 15, ty = tid >> 4;
    float acc[64];
#pragma unroll
    for (int i = 0; i < 64; i++) acc[i] = 0.f;
    int row0 = gy * 128;  // local row within slice
    for (int k0 = 0; k0 < HC; k0 += 16) {
#pragma unroll
        for (int q = 0; q < 2; q++) {
            int f = tid * 2 + q;
            // A: [128 rows x 16 k] -> transposed store As[k][r]
            int r = f >> 2, kk4 = (f & 3) * 4;
            int lrow = row0 + r;
            float a0 = 0.f, a1 = 0.f, a2 = 0.f, a3 = 0.f;
            if (lrow < SLICE_ROWS) {
                ushort4 u = *(const ushort4*)&A[(size_t)(row_base + lrow) * HC + k0 + kk4];
                a0 = bf2f(u.x); a1 = bf2f(u.y); a2 = bf2f(u.z); a3 = bf2f(u.w);
            }
            As[(kk4 + 0) * 132 + r] = a0;
            As[(kk4 + 1) * 132 + r] = a1;
            As[(kk4 + 2) * 132 + r] = a2;
            As[(kk4 + 3) * 132 + r] = a3;
            // B: [16 k x 128 cols]
            int kk = f >> 5, c4 = (f & 31) * 4;
            float4 w = *(const float4*)&B[(size_t)(k0 + kk) * HC + gx * 128 + c4];
            *(float4*)&Bs[kk * 132 + c4] = w;
        }
        __syncthreads();
#pragma unroll
        for (int kk = 0; kk < 16; kk++) {
            float4 a0 = *(float4*)&As[kk * 132 + ty * 8];
            float4 a1 = *(float4*)&As[kk * 132 + ty * 8 + 4];
            float4 b0 = *(float4*)&Bs[kk * 132 + tx * 8];
            float4 b1 = *(float4*)&Bs[kk * 132 + tx * 8 + 4];
            float a[8] = {a0.x, a0.y, a0.z, a0.w, a1.x, a1.y, a1.z, a1.w};
            float b[8] = {b0.x, b0.y, b0.z, b0.w, b1.x, b1.y, b1.z, b1.w};
#pragma unroll
            for (int i = 0; i < 8; i++)
#pragma unroll
                for (int j = 0; j < 8; j++) acc[i * 8 + j] += a[i] * b[j];
        }
        __syncthreads();
    }
#pragma unroll
    for (int i = 0; i < 8; i++) {
        int lrow = row0 + ty * 8 + i;
        if (lrow < SLICE_ROWS) {
            uint4 p;
            p.x = (unsigned int)f2bf(acc[i * 8 + 0]) | ((unsigned int)f2bf(acc[i * 8 + 1]) << 16);
            p.y = (unsigned int)f2bf(acc[i * 8 + 2]) | ((unsigned int)f2bf(acc[i * 8 + 3]) << 16);
            p.z = (unsigned int)f2bf(acc[i * 8 + 4]) | ((unsigned int)f2bf(acc[i * 8 + 5]) << 16);
            p.w = (unsigned int)f2bf(acc[i * 8 + 6]) | ((unsigned int)f2bf(acc[i * 8 + 7]) << 16);
            *(uint4*)&T[(size_t)lrow * HC + gx * 128 + tx * 8] = p;
        }
    }
}

// ---------------- per-node attention logits for layer 2 (h2 in bf16) ----------------
__global__ __launch_bounds__(256) void k_al2(const bf16_t* __restrict__ h2, const float* __restrict__ a2s,
                                             const float* __restrict__ a2d, float* __restrict__ al2s,
                                             float* __restrict__ al2d) {
    int tid = threadIdx.x, lane = tid & 63;
    int node = (blockIdx.x * 256 + tid) >> 6;
    const bf16_t* hr = h2 + (size_t)node * HC;
#pragma unroll
    for (int h = 0; h < NH; h++) {
        float v = bf2f(hr[h * 64 + lane]);
        float ps = v * a2s[h * 64 + lane];
        float pd = v * a2d[h * 64 + lane];
#pragma unroll
        for (int off = 1; off < 64; off <<= 1) {
            ps += __shfl_xor(ps, off, 64);
            pd += __shfl_xor(pd, off, 64);
        }
        if (lane == 0) {
            al2s[node * NH + h] = ps;
            al2d[node * NH + h] = pd;
        }
    }
}

// ---------------- layer 2: softmax + aggregation + fused mean-pool atomics ----------------
__global__ __launch_bounds__(256) void k_layer2pool(
    const bf16_t* __restrict__ h2, const float* __restrict__ al2s, const float* __restrict__ al2d,
    const int* __restrict__ rowptr, const int* __restrict__ csr, const float* __restrict__ b2,
    const int* __restrict__ batch, float* __restrict__ poolpart) {
    int tid = threadIdx.x, lane = tid & 63;
    int dst = (blockIdx.x * 256 + tid) >> 6;
    int rs = rowptr[dst], re = rowptr[dst + 1];
    float4 d0 = *(const float4*)&al2d[dst * NH];
    float4 d1 = *(const float4*)&al2d[dst * NH + 4];
    float ald[NH] = {d0.x, d0.y, d0.z, d0.w, d1.x, d1.y, d1.z, d1.w};
    // pass 1: lane-parallel max
    float m[NH];
#pragma unroll
    for (int h = 0; h < NH; h++) m[h] = -1e30f;
    for (int base = rs; base < re; base += 64) {
        int e = base + lane;
        if (e < re) {
            int s = csr[e];
            float4 p0 = *(const float4*)&al2s[s * NH];
            float4 p1 = *(const float4*)&al2s[s * NH + 4];
            float als[NH] = {p0.x, p0.y, p0.z, p0.w, p1.x, p1.y, p1.z, p1.w};
#pragma unroll
            for (int h = 0; h < NH; h++) {
                float ev = als[h] + ald[h];
                ev = ev > 0.f ? ev : 0.2f * ev;
                m[h] = fmaxf(m[h], ev);
            }
        }
    }
#pragma unroll
    for (int h = 0; h < NH; h++)
#pragma unroll
        for (int off = 1; off < 64; off <<= 1) m[h] = fmaxf(m[h], __shfl_xor(m[h], off, 64));
    // pass 2: sequential edges, lane = channel within head
    float den[NH], acc[NH];
#pragma unroll
    for (int h = 0; h < NH; h++) { den[h] = 0.f; acc[h] = 0.f; }
    for (int e = rs; e < re; e++) {
        int s = csr[e];
        float4 p0 = *(const float4*)&al2s[s * NH];
        float4 p1 = *(const float4*)&al2s[s * NH + 4];
        float als[NH] = {p0.x, p0.y, p0.z, p0.w, p1.x, p1.y, p1.z, p1.w};
        const bf16_t* hr = h2 + (size_t)s * HC;
#pragma unroll
        for (int h = 0; h < NH; h++) {
            float ev = als[h] + ald[h];
            ev = ev > 0.f ? ev : 0.2f * ev;
            float w = expf(ev - m[h]);
            den[h] += w;
            acc[h] += w * bf2f(hr[h * 64 + lane]);
        }
    }
    int g = batch[dst];
    int p = blockIdx.x & (NPART - 1);
    float* pp = poolpart + ((size_t)p * NG + g) * HC;
#pragma unroll
    for (int h = 0; h < NH; h++) {
        int col = h * 64 + lane;
        float v = acc[h] / den[h] + b2[col];
        v = v > 0.f ? v : expm1f(v);  // ELU
        atomicAdd(&pp[col], v);
    }
}

// ---------------- graph bounds (for counts) ----------------
__global__ void k_initb(int* __restrict__ gstart) {
    int i = blockIdx.x * 64 + threadIdx.x;
    if (i <= NG) gstart[i] = N_NODES;
}

__global__ void k_bounds(const int* __restrict__ batch, int* __restrict__ gstart) {
    int i = blockIdx.x * 256 + threadIdx.x;
    if (i >= N_NODES) return;
    int b = batch[i];
    if (i == 0) {
        for (int g = 0; g <= b; g++) gstart[g] = 0;
    } else {
        int bp = batch[i - 1];
        if (b != bp)
            for (int g = bp + 1; g <= b; g++) gstart[g] = i;
    }
}

// ---------------- reduce pooling partitions ----------------
__global__ void k_poolred(const float* __restrict__ poolpart, float* __restrict__ pooled) {
    int i = blockIdx.x * 256 + threadIdx.x;  // over NG*HC
    if (i >= NG * HC) return;
    float s = 0.f;
    for (int p = 0; p < NPART; p++) s += poolpart[(size_t)p * NG * HC + i];
    pooled[i] = s;
}

// ---------------- classifier ----------------
__global__ void k_cls(const float* __restrict__ pooled, const int* __restrict__ gstart,
                      const float* __restrict__ Wc, const float* __restrict__ bc,
                      float* __restrict__ out) {
    int i = blockIdx.x * 256 + threadIdx.x;
    if (i >= NG * 10) return;
    int g = i / 10, o = i % 10;
    float cnt = fmaxf((float)(gstart[g + 1] - gstart[g]), 1.0f);
    float acc = 0.f;
    for (int k = 0; k < HC; k++) acc += pooled[g * HC + k] * Wc[k * 10 + o];
    out[i] = acc / cnt + bc[o];
}

extern "C" void kernel_launch(void* const* d_in, const int* in_sizes, int n_in,
                              void* d_out, int out_size, void* d_ws, size_t ws_size,
                              hipStream_t stream) {
    const float* x   = (const float*)d_in[0];
    const int*   ei  = (const int*)d_in[1];
    const int*   bat = (const int*)d_in[2];
    const float* W1  = (const float*)d_in[3];
    const float* a1s = (const float*)d_in[4];
    const float* a1d = (const float*)d_in[5];
    const float* b1  = (const float*)d_in[6];
    const float* W2  = (const float*)d_in[7];
    const float* a2s = (const float*)d_in[8];
    const float* a2d = (const float*)d_in[9];
    const float* b2  = (const float*)d_in[10];
    const float* Wc  = (const float*)d_in[11];
    const float* bc  = (const float*)d_in[12];
    float* out = (float*)d_out;

    char* ws = (char*)d_ws;
    size_t off = 0;
    auto alloc = [&](size_t bytes) {
        size_t o = off;
        off += (bytes + 255) & ~(size_t)255;
        return o;
    };
    float*  wprep    = (float*)(ws + alloc(48 * 4));
    int*    rowptr   = (int*)(ws + alloc((size_t)(N_NODES + 1) * 4));
    int*    deg      = (int*)(ws + alloc((size_t)N_NODES * 4));
    int*    cursor   = (int*)(ws + alloc((size_t)N_NODES * 4));
    int*    part     = (int*)(ws + alloc(512 * 4));
    int*    gstart   = (int*)(ws + alloc(65 * 4));
    int*    csr      = (int*)(ws + alloc((size_t)EP * 4));
    bf16_t* x1b      = (bf16_t*)(ws + alloc((size_t)N_NODES * HC * 2));     // x1, then h2 (in-place)
    bf16_t* T        = (bf16_t*)(ws + alloc((size_t)SLICE_ROWS * HC * 2));  // GEMM slice temp
    float*  al2s     = (float*)(ws + alloc((size_t)N_NODES * NH * 4));
    float*  al2d     = (float*)(ws + alloc((size_t)N_NODES * NH * 4));
    float*  poolpart = (float*)(ws + alloc((size_t)NPART * NG * HC * 4));
    float*  pooled   = (float*)(ws + alloc((size_t)NG * HC * 4));
    // total ~121 MB

    hipMemsetAsync(deg, 0, (size_t)N_NODES * 4, stream);
    hipMemsetAsync(cursor, 0, (size_t)N_NODES * 4, stream);
    hipMemsetAsync(poolpart, 0, (size_t)NPART * NG * HC * 4, stream);

    k_prep<<<1, 64, 0, stream>>>(W1, a1s, a1d, wprep);
    k_deg<<<(EP + 255) / 256, 256, 0, stream>>>(ei, deg);
    k_scan1<<<SCAN_BLOCKS, 256, 0, stream>>>(deg, rowptr, part);
    k_scan2<<<1, 512, 0, stream>>>(part, rowptr);
    k_scan3<<<SCAN_BLOCKS, 256, 0, stream>>>(part, rowptr);
    k_scatter<<<(EP + 255) / 256, 256, 0, stream>>>(ei, rowptr, cursor, csr);
    k_layer1<<<N_NODES / 4, 256, 0, stream>>>(x, rowptr, csr, W1, wprep, b1, x1b);
    // in-place GEMM2 over 16 row slices: slice GEMM -> temp -> copy back over x1 rows
    for (int s = 0; s < NSLICE; s++) {
        k_gemm2<<<dim3(4, (SLICE_ROWS + 127) / 128), 256, 0, stream>>>(x1b, W2, T, s * SLICE_ROWS);
        hipMemcpyAsync(x1b + (size_t)s * SLICE_ROWS * HC, T,
                       (size_t)SLICE_ROWS * HC * 2, hipMemcpyDeviceToDevice, stream);
    }
    // x1b now holds h2 (bf16)
    k_al2<<<N_NODES / 4, 256, 0, stream>>>(x1b, a2s, a2d, al2s, al2d);
    k_initb<<<2, 64, 0, stream>>>(gstart);
    k_bounds<<<SCAN_BLOCKS, 256, 0, stream>>>(bat, gstart);
    k_layer2pool<<<N_NODES / 4, 256, 0, stream>>>(x1b, al2s, al2d, rowptr, csr, b2, bat, poolpart);
    k_poolred<<<(NG * HC + 255) / 256, 256, 0, stream>>>(poolpart, pooled);
    k_cls<<<3, 256, 0, stream>>>(pooled, gstart, Wc, bc, out);
}

// Round 3
// 1104.918 us; speedup vs baseline: 2.3736x; 2.3736x over previous
//
#include <hip/hip_runtime.h>
#include <math.h>

#define N_NODES 100000
#define N_EDGES 1600000
#define EP (N_EDGES + N_NODES)   // edges + self-loops = 1,700,000
#define NH 8
#define NC 64
#define NG 64
#define HC 512
#define SCAN_BLOCKS ((N_NODES + 255) / 256)   // 391
#define NPART 32                              // pooling atomic partitions
#define ASTRIDE 56                            // LDS row stride (shorts): 112B, 16B-aligned, ~2-way banks

typedef unsigned short bf16_t;
typedef __attribute__((ext_vector_type(8))) short short8;
typedef __attribute__((ext_vector_type(4))) float floatx4;

__device__ inline float bf2f(bf16_t u) {
    union { unsigned int i; float f; } x;
    x.i = (unsigned int)u << 16;
    return x.f;
}
__device__ inline bf16_t f2bf(float f) {
    union { float f; unsigned int i; } x;
    x.f = f;
    unsigned int b = x.i;
    return (bf16_t)((b + 0x7fffu + ((b >> 16) & 1u)) >> 16);
}
__device__ inline float u2flo(unsigned int u) {
    union { unsigned int i; float f; } x;
    x.i = u << 16;
    return x.f;
}
__device__ inline float u2fhi(unsigned int u) {
    union { unsigned int i; float f; } x;
    x.i = u & 0xffff0000u;
    return x.f;
}

// ---------------- prep: ws1[h][k] = sum_c W1[k][h*64+c]*a1s[h][c]; wd1 likewise ----------------
__global__ void k_prep(const float* __restrict__ W1, const float* __restrict__ a1s,
                       const float* __restrict__ a1d, float* __restrict__ wprep) {
    int t = threadIdx.x;  // need 48
    if (t < 48) {
        int isD = t >= 24;
        int tt = t % 24;
        int h = tt / 3, k = tt % 3;
        const float* a = isD ? a1d : a1s;
        float s = 0.f;
        for (int c = 0; c < 64; c++) s += W1[k * HC + h * 64 + c] * a[h * 64 + c];
        wprep[t] = s;  // [0..23]=ws1[h*3+k], [24..47]=wd1
    }
}

// ---------------- CSR build ----------------
__global__ void k_deg(const int* __restrict__ ei, int* __restrict__ deg) {
    int i = blockIdx.x * 256 + threadIdx.x;
    if (i >= EP) return;
    int d = (i < N_EDGES) ? ei[N_EDGES + i] : (i - N_EDGES);
    atomicAdd(&deg[d], 1);
}

__global__ void k_scan1(const int* __restrict__ deg, int* __restrict__ rowptr, int* __restrict__ part) {
    __shared__ int s[256];
    int t = threadIdx.x, i = blockIdx.x * 256 + t;
    int v = (i < N_NODES) ? deg[i] : 0;
    s[t] = v;
    __syncthreads();
    for (int off = 1; off < 256; off <<= 1) {
        int u = (t >= off) ? s[t - off] : 0;
        __syncthreads();
        s[t] += u;
        __syncthreads();
    }
    if (i < N_NODES) rowptr[i] = s[t] - v;  // exclusive
    if (t == 255) part[blockIdx.x] = s[t];
}

__global__ void k_scan2(int* __restrict__ part, int* __restrict__ rowptr) {
    __shared__ int s[512];
    int t = threadIdx.x;
    int v = (t < SCAN_BLOCKS) ? part[t] : 0;
    s[t] = v;
    __syncthreads();
    for (int off = 1; off < 512; off <<= 1) {
        int u = (t >= off) ? s[t - off] : 0;
        __syncthreads();
        s[t] += u;
        __syncthreads();
    }
    part[t] = s[t] - v;  // exclusive
    if (t == 0) rowptr[N_NODES] = EP;
}

__global__ void k_scan3(const int* __restrict__ part, int* __restrict__ rowptr) {
    int i = blockIdx.x * 256 + threadIdx.x;
    if (i < N_NODES) rowptr[i] += part[blockIdx.x];
}

__global__ void k_scatter(const int* __restrict__ ei, const int* __restrict__ rowptr,
                          int* __restrict__ cursor, int* __restrict__ csr) {
    int i = blockIdx.x * 256 + threadIdx.x;
    if (i >= EP) return;
    int s, d;
    if (i < N_EDGES) { s = ei[i]; d = ei[N_EDGES + i]; }
    else { s = i - N_EDGES; d = s; }
    int pos = rowptr[d] + atomicAdd(&cursor[d], 1);
    csr[pos] = s;
}

// ---------------- W2 -> bf16 transposed: W2T[n][k] = W2[k][n] ----------------
__global__ void k_w2t(const float* __restrict__ W2, bf16_t* __restrict__ W2T) {
    int i = blockIdx.x * 256 + threadIdx.x;  // over 512*512
    int n = i >> 9, k = i & 511;
    W2T[i] = f2bf(W2[k * HC + n]);
}

// ---------------- layer 1 (fused: rank-3 trick, no h1 materialization), bf16 output --------
__global__ __launch_bounds__(256) void k_layer1(
    const float* __restrict__ x, const int* __restrict__ rowptr, const int* __restrict__ csr,
    const float* __restrict__ W1, const float* __restrict__ wprep, const float* __restrict__ b1,
    bf16_t* __restrict__ x1) {
    __shared__ float w1s[1536];
    __shared__ float wp[48];
    int tid = threadIdx.x;
    for (int i = tid; i < 1536; i += 256) w1s[i] = W1[i];
    if (tid < 48) wp[tid] = wprep[tid];
    __syncthreads();
    int lane = tid & 63;
    int dst = (blockIdx.x * 256 + tid) >> 6;  // grid exactly covers N
    int rs = rowptr[dst], re = rowptr[dst + 1];
    float xd0 = x[dst * 3], xd1 = x[dst * 3 + 1], xd2 = x[dst * 3 + 2];
    float ald[NH];
#pragma unroll
    for (int h = 0; h < NH; h++)
        ald[h] = xd0 * wp[24 + h * 3] + xd1 * wp[24 + h * 3 + 1] + xd2 * wp[24 + h * 3 + 2];
    // pass 1: per-head max (lane-parallel over edges)
    float m[NH];
#pragma unroll
    for (int h = 0; h < NH; h++) m[h] = -3e38f;
    for (int base = rs; base < re; base += 64) {
        int e = base + lane;
        if (e < re) {
            int s = csr[e];
            float s0 = x[s * 3], s1 = x[s * 3 + 1], s2 = x[s * 3 + 2];
#pragma unroll
            for (int h = 0; h < NH; h++) {
                float ev = s0 * wp[h * 3] + s1 * wp[h * 3 + 1] + s2 * wp[h * 3 + 2] + ald[h];
                ev = fmaxf(ev, 0.2f * ev);
                m[h] = fmaxf(m[h], ev);
            }
        }
    }
#pragma unroll
    for (int h = 0; h < NH; h++)
#pragma unroll
        for (int off = 1; off < 64; off <<= 1) m[h] = fmaxf(m[h], __shfl_xor(m[h], off, 64));
    // pass 2: den + 3-vector accumulators (lane-parallel over edges)
    float den[NH], c0[NH], c1[NH], c2[NH];
#pragma unroll
    for (int h = 0; h < NH; h++) { den[h] = 0.f; c0[h] = 0.f; c1[h] = 0.f; c2[h] = 0.f; }
    for (int base = rs; base < re; base += 64) {
        int e = base + lane;
        if (e < re) {
            int s = csr[e];
            float s0 = x[s * 3], s1 = x[s * 3 + 1], s2 = x[s * 3 + 2];
#pragma unroll
            for (int h = 0; h < NH; h++) {
                float ev = s0 * wp[h * 3] + s1 * wp[h * 3 + 1] + s2 * wp[h * 3 + 2] + ald[h];
                ev = fmaxf(ev, 0.2f * ev);
                float w = __expf(ev - m[h]);
                den[h] += w;
                c0[h] += w * s0;
                c1[h] += w * s1;
                c2[h] += w * s2;
            }
        }
    }
#pragma unroll
    for (int h = 0; h < NH; h++) {
#pragma unroll
        for (int off = 1; off < 64; off <<= 1) {
            den[h] += __shfl_xor(den[h], off, 64);
            c0[h] += __shfl_xor(c0[h], off, 64);
            c1[h] += __shfl_xor(c1[h], off, 64);
            c2[h] += __shfl_xor(c2[h], off, 64);
        }
    }
    // epilogue: project 3-vec through W1 head-slice, bias, ELU, store bf16
#pragma unroll
    for (int h = 0; h < NH; h++) {
        int col = h * 64 + lane;
        float v = c0[h] * w1s[col] + c1[h] * w1s[512 + col] + c2[h] * w1s[1024 + col];
        v = v / den[h] + b1[col];
        v = v > 0.f ? v : (__expf(v) - 1.f);
        x1[(size_t)dst * HC + col] = f2bf(v);
    }
}

// ---------------- GEMM2: Out = A @ W2 via bf16 MFMA (A bf16, BT = W2^T bf16) ----------------
// 128x128 tile, BK=32, 4 waves in 2x2 grid, each wave 4x4 of 16x16x32 MFMA.
__global__ __launch_bounds__(256) void k_gemm2(const bf16_t* __restrict__ A,
                                               const bf16_t* __restrict__ BT,
                                               bf16_t* __restrict__ Out,
                                               int row_base, int nrows) {
    __shared__ short As[128 * ASTRIDE];
    __shared__ short Bs[128 * ASTRIDE];
    int tid = threadIdx.x;
    int lane = tid & 63, wave = tid >> 6;
    int wm = wave & 1, wn = wave >> 1;
    int lm = lane & 15, quad = lane >> 4;
    int gx = blockIdx.x, gy = blockIdx.y;
    floatx4 acc[4][4];
#pragma unroll
    for (int mi = 0; mi < 4; mi++)
#pragma unroll
        for (int ni = 0; ni < 4; ni++) acc[mi][ni] = (floatx4){0.f, 0.f, 0.f, 0.f};

    for (int k0 = 0; k0 < HC; k0 += 32) {
        uint4 av[2], bv[2];
        int rr[2], pp[2];
#pragma unroll
        for (int q = 0; q < 2; q++) {
            int c = tid * 2 + q;      // 0..511 : 128 rows x 4 16B-chunks
            rr[q] = c >> 2;
            pp[q] = c & 3;
            int grow = gy * 128 + rr[q];
            if (grow < nrows)
                av[q] = *(const uint4*)&A[(size_t)(row_base + grow) * HC + k0 + pp[q] * 8];
            else { av[q].x = 0u; av[q].y = 0u; av[q].z = 0u; av[q].w = 0u; }
            bv[q] = *(const uint4*)&BT[(size_t)(gx * 128 + rr[q]) * HC + k0 + pp[q] * 8];
        }
        __syncthreads();
#pragma unroll
        for (int q = 0; q < 2; q++) {
            *(uint4*)&As[rr[q] * ASTRIDE + pp[q] * 8] = av[q];
            *(uint4*)&Bs[rr[q] * ASTRIDE + pp[q] * 8] = bv[q];
        }
        __syncthreads();
        short8 af[4], bf[4];
#pragma unroll
        for (int mi = 0; mi < 4; mi++)
            af[mi] = *(const short8*)&As[(wm * 64 + mi * 16 + lm) * ASTRIDE + quad * 8];
#pragma unroll
        for (int ni = 0; ni < 4; ni++)
            bf[ni] = *(const short8*)&Bs[(wn * 64 + ni * 16 + lm) * ASTRIDE + quad * 8];
#pragma unroll
        for (int mi = 0; mi < 4; mi++)
#pragma unroll
            for (int ni = 0; ni < 4; ni++)
                acc[mi][ni] = __builtin_amdgcn_mfma_f32_16x16x32_bf16(af[mi], bf[ni], acc[mi][ni], 0, 0, 0);
    }
    // epilogue: C row = quad*4+reg (m), col = lane&15 (n)
#pragma unroll
    for (int mi = 0; mi < 4; mi++)
#pragma unroll
        for (int ni = 0; ni < 4; ni++) {
            int col = gx * 128 + wn * 64 + ni * 16 + lm;
#pragma unroll
            for (int rg = 0; rg < 4; rg++) {
                int lrow = gy * 128 + wm * 64 + mi * 16 + quad * 4 + rg;
                if (lrow < nrows) Out[(size_t)lrow * HC + col] = f2bf(acc[mi][ni][rg]);
            }
        }
}

// ---------------- al2: per-node attention logits + IN-PLACE row permute ----------------
// permuted layout: h2p[node][c'] with c' = l*8 + h  <-  h2[node][h*64 + l]
__global__ __launch_bounds__(256) void k_al2(bf16_t* __restrict__ h2,
                                             const float* __restrict__ a2s,
                                             const float* __restrict__ a2d,
                                             float* __restrict__ al2s, float* __restrict__ al2d) {
    __shared__ unsigned short rowbuf[4][512];
    int tid = threadIdx.x, lane = tid & 63, wave = tid >> 6;
    int node = blockIdx.x * 4 + wave;
    uint4 v = *(const uint4*)&h2[(size_t)node * HC + lane * 8];  // orig c = lane*8 .. +7 (one head)
    float f0 = u2flo(v.x), f1 = u2fhi(v.x), f2 = u2flo(v.y), f3 = u2fhi(v.y);
    float f4 = u2flo(v.z), f5 = u2fhi(v.z), f6 = u2flo(v.w), f7 = u2fhi(v.w);
    float4 sa = *(const float4*)&a2s[lane * 8];
    float4 sb = *(const float4*)&a2s[lane * 8 + 4];
    float4 da = *(const float4*)&a2d[lane * 8];
    float4 db = *(const float4*)&a2d[lane * 8 + 4];
    float ps = f0 * sa.x + f1 * sa.y + f2 * sa.z + f3 * sa.w + f4 * sb.x + f5 * sb.y + f6 * sb.z + f7 * sb.w;
    float pd = f0 * da.x + f1 * da.y + f2 * da.z + f3 * da.w + f4 * db.x + f5 * db.y + f6 * db.z + f7 * db.w;
#pragma unroll
    for (int off = 1; off < 8; off <<= 1) {
        ps += __shfl_xor(ps, off, 64);
        pd += __shfl_xor(pd, off, 64);
    }
    if ((lane & 7) == 0) {
        al2s[node * NH + (lane >> 3)] = ps;
        al2d[node * NH + (lane >> 3)] = pd;
    }
    // in-place permute via per-wave LDS roundtrip
    *(uint4*)&rowbuf[wave][lane * 8] = v;
    unsigned short t[8];
#pragma unroll
    for (int j = 0; j < 8; j++) t[j] = rowbuf[wave][j * 64 + lane];  // orig c = j*64+lane -> slot j
    uint4 o;
    o.x = (unsigned int)t[0] | ((unsigned int)t[1] << 16);
    o.y = (unsigned int)t[2] | ((unsigned int)t[3] << 16);
    o.z = (unsigned int)t[4] | ((unsigned int)t[5] << 16);
    o.w = (unsigned int)t[6] | ((unsigned int)t[7] << 16);
    *(uint4*)&h2[(size_t)node * HC + lane * 8] = o;
}

// ---------------- layer 2: lane-parallel softmax weights + broadcast aggregation + pool ------
__global__ __launch_bounds__(256) void k_layer2pool(
    const bf16_t* __restrict__ h2p, const float* __restrict__ al2s, const float* __restrict__ al2d,
    const int* __restrict__ rowptr, const int* __restrict__ csr, const float* __restrict__ b2,
    const int* __restrict__ batch, float* __restrict__ poolpart) {
    __shared__ float wlds[4][512];
    __shared__ int slds[4][64];
    int tid = threadIdx.x, lane = tid & 63, wave = tid >> 6;
    int dst = blockIdx.x * 4 + wave;
    int rs = rowptr[dst], re = rowptr[dst + 1];
    float4 d0 = *(const float4*)&al2d[dst * NH];
    float4 d1 = *(const float4*)&al2d[dst * NH + 4];
    float ald[NH] = {d0.x, d0.y, d0.z, d0.w, d1.x, d1.y, d1.z, d1.w};
    // pass 1: lane-parallel max
    float m[NH];
#pragma unroll
    for (int h = 0; h < NH; h++) m[h] = -3e38f;
    for (int base = rs; base < re; base += 64) {
        int e = base + lane;
        if (e < re) {
            int s = csr[e];
            float4 p0 = *(const float4*)&al2s[s * NH];
            float4 p1 = *(const float4*)&al2s[s * NH + 4];
            float als[NH] = {p0.x, p0.y, p0.z, p0.w, p1.x, p1.y, p1.z, p1.w};
#pragma unroll
            for (int h = 0; h < NH; h++) {
                float ev = als[h] + ald[h];
                ev = fmaxf(ev, 0.2f * ev);
                m[h] = fmaxf(m[h], ev);
            }
        }
    }
#pragma unroll
    for (int h = 0; h < NH; h++)
#pragma unroll
        for (int off = 1; off < 64; off <<= 1) m[h] = fmaxf(m[h], __shfl_xor(m[h], off, 64));
    // pass 2: per chunk, lane-parallel weights -> LDS, then broadcast aggregation
    float den[NH], acc[NH];
#pragma unroll
    for (int h = 0; h < NH; h++) { den[h] = 0.f; acc[h] = 0.f; }
    for (int base = rs; base < re; base += 64) {
        int e = base + lane;
        int cl = re - base; if (cl > 64) cl = 64;
        float w[NH];
        int s = 0;
        if (e < re) {
            s = csr[e];
            float4 p0 = *(const float4*)&al2s[s * NH];
            float4 p1 = *(const float4*)&al2s[s * NH + 4];
            float als[NH] = {p0.x, p0.y, p0.z, p0.w, p1.x, p1.y, p1.z, p1.w};
#pragma unroll
            for (int h = 0; h < NH; h++) {
                float ev = als[h] + ald[h];
                ev = fmaxf(ev, 0.2f * ev);
                w[h] = __expf(ev - m[h]);
                den[h] += w[h];
            }
        } else {
#pragma unroll
            for (int h = 0; h < NH; h++) w[h] = 0.f;
        }
        slds[wave][lane] = s;
        *(float4*)&wlds[wave][lane * 8] = make_float4(w[0], w[1], w[2], w[3]);
        *(float4*)&wlds[wave][lane * 8 + 4] = make_float4(w[4], w[5], w[6], w[7]);
        // same-wave LDS write->read: in-order LDS pipe + compiler lgkmcnt
        for (int j = 0; j < cl; j++) {
            int s2 = slds[wave][j];
            float4 wa = *(const float4*)&wlds[wave][j * 8];
            float4 wb = *(const float4*)&wlds[wave][j * 8 + 4];
            uint4 v = *(const uint4*)&h2p[(size_t)s2 * HC + lane * 8];
            acc[0] += wa.x * u2flo(v.x);
            acc[1] += wa.y * u2fhi(v.x);
            acc[2] += wa.z * u2flo(v.y);
            acc[3] += wa.w * u2fhi(v.y);
            acc[4] += wb.x * u2flo(v.z);
            acc[5] += wb.y * u2fhi(v.z);
            acc[6] += wb.z * u2flo(v.w);
            acc[7] += wb.w * u2fhi(v.w);
        }
    }
#pragma unroll
    for (int h = 0; h < NH; h++)
#pragma unroll
        for (int off = 1; off < 64; off <<= 1) den[h] += __shfl_xor(den[h], off, 64);
    int g = batch[dst];
    float* pp = poolpart + ((size_t)(blockIdx.x & (NPART - 1)) * NG + g) * HC;
#pragma unroll
    for (int h = 0; h < NH; h++) {
        int col = h * 64 + lane;  // slot h of lane <-> orig channel h*64+lane
        float v = acc[h] / den[h] + b2[col];
        v = v > 0.f ? v : (__expf(v) - 1.f);
        atomicAdd(&pp[col], v);
    }
}

// ---------------- graph bounds (for counts) ----------------
__global__ void k_initb(int* __restrict__ gstart) {
    int i = blockIdx.x * 64 + threadIdx.x;
    if (i <= NG) gstart[i] = N_NODES;
}

__global__ void k_bounds(const int* __restrict__ batch, int* __restrict__ gstart) {
    int i = blockIdx.x * 256 + threadIdx.x;
    if (i >= N_NODES) return;
    int b = batch[i];
    if (i == 0) {
        for (int g = 0; g <= b; g++) gstart[g] = 0;
    } else {
        int bp = batch[i - 1];
        if (b != bp)
            for (int g = bp + 1; g <= b; g++) gstart[g] = i;
    }
}

// ---------------- reduce pooling partitions ----------------
__global__ void k_poolred(const float* __restrict__ poolpart, float* __restrict__ pooled) {
    int i = blockIdx.x * 256 + threadIdx.x;  // over NG*HC
    if (i >= NG * HC) return;
    float s = 0.f;
    for (int p = 0; p < NPART; p++) s += poolpart[(size_t)p * NG * HC + i];
    pooled[i] = s;
}

// ---------------- classifier ----------------
__global__ void k_cls(const float* __restrict__ pooled, const int* __restrict__ gstart,
                      const float* __restrict__ Wc, const float* __restrict__ bc,
                      float* __restrict__ out) {
    int i = blockIdx.x * 256 + threadIdx.x;
    if (i >= NG * 10) return;
    int g = i / 10, o = i % 10;
    float cnt = fmaxf((float)(gstart[g + 1] - gstart[g]), 1.0f);
    float acc = 0.f;
    for (int k = 0; k < HC; k++) acc += pooled[g * HC + k] * Wc[k * 10 + o];
    out[i] = acc / cnt + bc[o];
}

extern "C" void kernel_launch(void* const* d_in, const int* in_sizes, int n_in,
                              void* d_out, int out_size, void* d_ws, size_t ws_size,
                              hipStream_t stream) {
    const float* x   = (const float*)d_in[0];
    const int*   ei  = (const int*)d_in[1];
    const int*   bat = (const int*)d_in[2];
    const float* W1  = (const float*)d_in[3];
    const float* a1s = (const float*)d_in[4];
    const float* a1d = (const float*)d_in[5];
    const float* b1  = (const float*)d_in[6];
    const float* W2  = (const float*)d_in[7];
    const float* a2s = (const float*)d_in[8];
    const float* a2d = (const float*)d_in[9];
    const float* b2  = (const float*)d_in[10];
    const float* Wc  = (const float*)d_in[11];
    const float* bc  = (const float*)d_in[12];
    float* out = (float*)d_out;

    char* ws = (char*)d_ws;
    size_t off = 0;
    auto alloc = [&](size_t bytes) {
        size_t o = off;
        off += (bytes + 255) & ~(size_t)255;
        return o;
    };
    float*  wprep    = (float*)(ws + alloc(48 * 4));
    int*    rowptr   = (int*)(ws + alloc((size_t)(N_NODES + 1) * 4));
    int*    deg      = (int*)(ws + alloc((size_t)N_NODES * 4));
    int*    cursor   = (int*)(ws + alloc((size_t)N_NODES * 4));   // contiguous with deg
    int*    part     = (int*)(ws + alloc(512 * 4));
    int*    gstart   = (int*)(ws + alloc(65 * 4));
    int*    csr      = (int*)(ws + alloc((size_t)EP * 4));
    bf16_t* x1b      = (bf16_t*)(ws + alloc((size_t)N_NODES * HC * 2));
    float*  al2s     = (float*)(ws + alloc((size_t)N_NODES * NH * 4));
    float*  al2d     = (float*)(ws + alloc((size_t)N_NODES * NH * 4));
    float*  poolpart = (float*)(ws + alloc((size_t)NPART * NG * HC * 4));
    float*  pooled   = (float*)(ws + alloc((size_t)NG * HC * 4));
    // W2T (512x512 bf16 = 512KB) aliases deg+cursor (800KB, dead after k_scatter)
    bf16_t* W2T = (bf16_t*)deg;

    // GEMM slicing tier from remaining workspace (deterministic across calls)
    size_t rem = (ws_size > off) ? ws_size - off : 0;
    int nslices, srows;
    if (rem >= (size_t)N_NODES * HC * 2)      { nslices = 1;  srows = N_NODES; }
    else if (rem >= (size_t)25000 * HC * 2)   { nslices = 4;  srows = 25000; }
    else                                      { nslices = 16; srows = 6250; }
    bf16_t* T = (bf16_t*)(ws + alloc((size_t)srows * HC * 2));
    bf16_t* h2 = (nslices == 1) ? T : x1b;

    hipMemsetAsync(deg, 0, (size_t)N_NODES * 4, stream);
    hipMemsetAsync(cursor, 0, (size_t)N_NODES * 4, stream);
    hipMemsetAsync(poolpart, 0, (size_t)NPART * NG * HC * 4, stream);

    k_prep<<<1, 64, 0, stream>>>(W1, a1s, a1d, wprep);
    k_deg<<<(EP + 255) / 256, 256, 0, stream>>>(ei, deg);
    k_scan1<<<SCAN_BLOCKS, 256, 0, stream>>>(deg, rowptr, part);
    k_scan2<<<1, 512, 0, stream>>>(part, rowptr);
    k_scan3<<<SCAN_BLOCKS, 256, 0, stream>>>(part, rowptr);
    k_scatter<<<(EP + 255) / 256, 256, 0, stream>>>(ei, rowptr, cursor, csr);
    k_w2t<<<(HC * HC + 255) / 256, 256, 0, stream>>>(W2, W2T);  // after scatter: aliases deg/cursor
    k_layer1<<<N_NODES / 4, 256, 0, stream>>>(x, rowptr, csr, W1, wprep, b1, x1b);
    if (nslices == 1) {
        k_gemm2<<<dim3(4, (N_NODES + 127) / 128), 256, 0, stream>>>(x1b, W2T, h2, 0, N_NODES);
    } else {
        for (int s = 0; s < nslices; s++) {
            k_gemm2<<<dim3(4, (srows + 127) / 128), 256, 0, stream>>>(x1b, W2T, T, s * srows, srows);
            hipMemcpyAsync(x1b + (size_t)s * srows * HC, T, (size_t)srows * HC * 2,
                           hipMemcpyDeviceToDevice, stream);
        }
    }
    k_al2<<<N_NODES / 4, 256, 0, stream>>>(h2, a2s, a2d, al2s, al2d);
    k_initb<<<2, 64, 0, stream>>>(gstart);
    k_bounds<<<SCAN_BLOCKS, 256, 0, stream>>>(bat, gstart);
    k_layer2pool<<<N_NODES / 4, 256, 0, stream>>>(h2, al2s, al2d, rowptr, csr, b2, bat, poolpart);
    k_poolred<<<(NG * HC + 255) / 256, 256, 0, stream>>>(poolpart, pooled);
    k_cls<<<3, 256, 0, stream>>>(pooled, gstart, Wc, bc, out);
}